// Round 4
// baseline (4179.751 us; speedup 1.0000x reference)
//
#include <hip/hip_runtime.h>
#include <math.h>

#define BATCH 32
#define TFRAMES 1024
#define NBINS 257
#define NFFT 512
#define HOP 160
#define LOUT 163680
#define XPLEN 164192
#define NITER 32
#define FPW 4                        // frames per wave
#define WSTRIDE (FPW*HOP)            // 640  (per-wave strip stride)
#define BSTRIDE (2*WSTRIDE)          // 1280 (per-block stride, 2 waves)
#define HALO (NFFT - HOP)            // 352
#define SPAN (BSTRIDE + HALO)        // 1632 (block OLA span)
#define BXP ((size_t)BATCH*XPLEN)    // floats per X buffer

#define P(i) ((i) + ((i) >> 5))      // LDS pad: 2-way max on stride-1/64 patterns

__device__ __forceinline__ float cosr(float x){ return __builtin_amdgcn_cosf(x); }
__device__ __forceinline__ float sinr(float x){ return __builtin_amdgcn_sinf(x); }
__device__ __forceinline__ void wsync(){
    __builtin_amdgcn_fence(__ATOMIC_SEQ_CST, "wavefront");
    __builtin_amdgcn_wave_barrier();
}

struct Tw { float c1,s1,c2,s2,c3,s3; };
__device__ __forceinline__ Tw twset(float x){
    Tw t; float c=cosr(x), s=sinr(x);
    t.c1=c; t.s1=s;
    t.c2=c*c-s*s; t.s2=2.f*c*s;
    t.c3=t.c2*c-t.s2*s; t.s3=t.c2*s+t.s2*c;
    return t;
}

template<int SIGN, bool TWID>
__device__ __forceinline__ void bfly4(const float xr[4], const float xi[4],
                                      const Tw& t, float yr[4], float yi[4]){
    constexpr float SG = (SIGN>0)?1.f:-1.f;
    float apc_r=xr[0]+xr[2], apc_i=xi[0]+xi[2];
    float amc_r=xr[0]-xr[2], amc_i=xi[0]-xi[2];
    float bpd_r=xr[1]+xr[3], bpd_i=xi[1]+xi[3];
    float bmd_r=xr[1]-xr[3], bmd_i=xi[1]-xi[3];
    yr[0]=apc_r+bpd_r; yi[0]=apc_i+bpd_i;
    float u2r=apc_r-bpd_r, u2i=apc_i-bpd_i;
    float u1r=amc_r-SG*bmd_i, u1i=amc_i+SG*bmd_r;
    float u3r=amc_r+SG*bmd_i, u3i=amc_i-SG*bmd_r;
    if (TWID){
        float s1=SG*t.s1, s2=SG*t.s2, s3=SG*t.s3;
        yr[1]=t.c1*u1r-s1*u1i; yi[1]=t.c1*u1i+s1*u1r;
        yr[2]=t.c2*u2r-s2*u2i; yi[2]=t.c2*u2i+s2*u2r;
        yr[3]=t.c3*u3r-s3*u3i; yi[3]=t.c3*u3i+s3*u3r;
    } else {
        yr[1]=u1r; yi[1]=u1i; yr[2]=u2r; yi[2]=u2i; yr[3]=u3r; yi[3]=u3i;
    }
}

// 256-pt complex FFT per wave, radix-4 Stockham, regs in/out, ONE LDS buffer.
// Safe because LDS ops of a wave complete in program order (write-all/fence/
// read-all/fence), so WAR across stages cannot be violated.
template<int SIGN>
__device__ __forceinline__ void fft256reg(float xr[4], float xi[4],
                                          float* br, float* bi,
                                          const Tw& tw0, const Tw& tw1, const Tw& tw2,
                                          int lane){
    float yr[4], yi[4], ar[4], ai[4];
    bfly4<SIGN,true>(xr, xi, tw0, yr, yi);
    { int o = 4*lane;
#pragma unroll
      for (int c=0;c<4;++c){ br[P(o+c)]=yr[c]; bi[P(o+c)]=yi[c]; } }
    wsync();
#pragma unroll
    for (int c=0;c<4;++c){ ar[c]=br[P(lane+64*c)]; ai[c]=bi[P(lane+64*c)]; }
    wsync();
    bfly4<SIGN,true>(ar, ai, tw1, yr, yi);
    { int o = (lane&3) + 16*(lane>>2);
#pragma unroll
      for (int c=0;c<4;++c){ br[P(o+4*c)]=yr[c]; bi[P(o+4*c)]=yi[c]; } }
    wsync();
#pragma unroll
    for (int c=0;c<4;++c){ ar[c]=br[P(lane+64*c)]; ai[c]=bi[P(lane+64*c)]; }
    wsync();
    bfly4<SIGN,true>(ar, ai, tw2, yr, yi);
    { int o = (lane&15) + 64*(lane>>4);
#pragma unroll
      for (int c=0;c<4;++c){ br[P(o+16*c)]=yr[c]; bi[P(o+16*c)]=yi[c]; } }
    wsync();
#pragma unroll
    for (int c=0;c<4;++c){ ar[c]=br[P(lane+64*c)]; ai[c]=bi[P(lane+64*c)]; }
    wsync();
    bfly4<SIGN,false>(ar, ai, tw0, xr, xi);
}

// ============================================================
// k_init: wsqi (NOLA inverse) + zero X0,X1
// ============================================================
__global__ __launch_bounds__(256) void k_init(const float* __restrict__ win,
                                              float* __restrict__ wsqi,
                                              float4* __restrict__ Z){
    int gid = blockIdx.x*256 + threadIdx.x;
    int stride = gridDim.x*256;
    float4 z4 = make_float4(0.f,0.f,0.f,0.f);
    for (int u = gid; u < (int)(2*BXP/4); u += stride) Z[u] = z4;
    for (int i = gid; i < XPLEN; i += stride){
        int n = i;
        int tmax = n / HOP; if (tmax > TFRAMES-1) tmax = TFRAMES-1;
        int tmin = (n - (NFFT-1) + (HOP-1)) / HOP; if (tmin < 0) tmin = 0;
        float acc = 0.f;
        for (int t = tmin; t <= tmax; ++t){ float w = win[n - t*HOP]; acc += w*w; }
        wsqi[i] = 1.0f / (acc > 1e-11f ? acc : 1.0f);
    }
}

// istft tail: S regs (mirror staged in buf incl Nyquist) -> c2r pack -> inv FFT
// -> window -> LDS-atomic OLA into block sacc
__device__ __forceinline__ void istft_tail(float sr_[4], float si_[4],
                                           float* br, float* bi,
                                           const Tw& tw0, const Tw& tw1, const Tw& tw2,
                                           const float twc[4], const float tws[4],
                                           const float wA[4], const float wB[4],
                                           int lane, int off, float* sacc){
    float pr[4], pi[4];
#pragma unroll
    for (int c=0;c<4;++c){
        int k = lane + 64*c;
        float yr = br[P(256-k)], yi = bi[P(256-k)];
        float Xer = 0.5f*(sr_[c]+yr), Xei = 0.5f*(si_[c]-yi);
        float Dr = sr_[c]-yr, Di = si_[c]+yi;
        float Xor = 0.5f*(twc[c]*Dr - tws[c]*Di);
        float Xoi = 0.5f*(twc[c]*Di + tws[c]*Dr);
        pr[c] = Xer - Xoi;
        pi[c] = Xei + Xor;
    }
    wsync();
    fft256reg<+1>(pr, pi, br, bi, tw0, tw1, tw2, lane);
    constexpr float SC = 1.f/256.f;
#pragma unroll
    for (int c=0;c<4;++c){
        int m = lane + 64*c;
        atomicAdd(&sacc[off + 2*m],     pr[c]*wA[c]*SC);
        atomicAdd(&sacc[off + 2*m + 1], pi[c]*wB[c]*SC);
    }
    wsync();
}

// block-level store: interior plain float2, halos via global atomics
__device__ __forceinline__ void block_store(float* __restrict__ Xw, int b, int bx,
                                            const float* sacc, int tid){
    float* Xnb = Xw + (size_t)b*XPLEN + (size_t)bx*BSTRIDE;
#pragma unroll
    for (int j=0;j<4;++j){
        int u = tid + 128*j;
        if (u < (BSTRIDE-HALO)/2)
            ((float2*)(Xnb+HALO))[u] = ((const float2*)(sacc+HALO))[u];
    }
#pragma unroll
    for (int j=0;j<3;++j){
        int i = tid + 128*j;
        if (i < HALO){
            unsafeAtomicAdd(Xnb + i, sacc[i]);
            unsafeAtomicAdd(Xnb + BSTRIDE + i, sacc[BSTRIDE + i]);
        }
    }
}

// ============================================================
// k_gl: one Griffin-Lim iteration. block = 2 waves x 4 frames, shared OLA.
// ============================================================
__global__ __launch_bounds__(128,4) void k_gl(const float* __restrict__ Xr,
                                              float* __restrict__ Xw,
                                              float* __restrict__ Xz,
                                              const float* __restrict__ mag,
                                              const float* __restrict__ win,
                                              const float* __restrict__ wsq){
    __shared__ float sacc[SPAN];
    __shared__ float FR[2][272], FI[2][272];
    int tid = threadIdx.x, w = tid>>6, lane = tid&63;
    int b = blockIdx.y, bx = blockIdx.x;

    // zero rotation buffer (fully read last iteration, written next iteration)
    {
        float4 z4 = make_float4(0.f,0.f,0.f,0.f);
        int gid = (b*128 + bx)*128 + tid;                // 524288 threads
        float4* C4 = (float4*)Xz;
        const int TOT4 = (int)(BXP/4);
#pragma unroll
        for (int j=0;j<3;++j){ int u = gid + j*524288; if (u < TOT4) C4[u]=z4; }
    }

    float *br = FR[w], *bi = FI[w];

    // per-wave constants (no trig in frame loop)
    Tw tw0 = twset((float)lane * (1.f/256.f));
    Tw tw1 = twset((float)(lane>>2) * (1.f/64.f));
    Tw tw2 = twset((float)(lane>>4) * (1.f/16.f));
    float twc[4], tws[4], wA[4], wB[4];
#pragma unroll
    for (int c=0;c<4;++c){
        int k = lane + 64*c;
        float x = (float)k * (1.f/512.f);
        twc[c]=cosr(x); tws[c]=sinr(x);
        float2 wv = ((const float2*)win)[k];
        wA[c]=wv.x; wB[c]=wv.y;
    }
#pragma unroll
    for (int j=0;j<13;++j){ int u = tid + 128*j; if (u < SPAN) sacc[u]=0.f; }
    __syncthreads();

    const float* Xb = Xr + (size_t)b*XPLEN;
    const float* magb = mag + ((size_t)b*TFRAMES)*NBINS;
    int t0 = (bx*2 + w)*FPW;

#pragma unroll 1
    for (int f=0; f<FPW; ++f){
        int t = t0 + f;
        float fr[4], fi[4];
        bool edge = (t < 2) | (t >= TFRAMES-2);
        if (!edge){
            const float2* a2 = (const float2*)(Xb + (size_t)t*HOP);
            const float2* q2 = (const float2*)(wsq + (size_t)t*HOP);
#pragma unroll
            for (int c=0;c<4;++c){
                int m = lane + 64*c;
                float2 av = a2[m], qv = q2[m];
                fr[c] = av.x*qv.x*wA[c];
                fi[c] = av.y*qv.y*wB[c];
            }
        } else {
#pragma unroll
            for (int c=0;c<4;++c){
                int m = lane + 64*c;
                int p0 = t*HOP + 2*m, p1 = p0+1;
                int n0 = (p0<256)?(512-p0):((p0>=LOUT+256)?(2*LOUT+510-p0):p0);
                int n1 = (p1<256)?(512-p1):((p1>=LOUT+256)?(2*LOUT+510-p1):p1);
                fr[c] = Xb[n0]*wsq[n0]*wA[c];
                fi[c] = Xb[n1]*wsq[n1]*wB[c];
            }
        }
        // forward FFT of packed frame
        fft256reg<-1>(fr, fi, br, bi, tw0, tw1, tw2, lane);
        float z0r = fr[0], z0i = fi[0];          // lane0: Z[0] for Nyquist
        // stage Z for mirror exchange (r2c unpack)
#pragma unroll
        for (int c=0;c<4;++c){ int k=lane+64*c; br[P(k)]=fr[c]; bi[P(k)]=fi[c]; }
        wsync();
        float sr_[4], si_[4];
        const float* magp = magb + (size_t)t*NBINS;
#pragma unroll
        for (int c=0;c<4;++c){
            int k = lane + 64*c;
            int mk = (256 - k) & 255;
            float yr = br[P(mk)], yi = bi[P(mk)];
            float zr = fr[c], zi = fi[c];
            float Xer = 0.5f*(zr+yr), Xei = 0.5f*(zi-yi);
            float Dr = zr-yr, Di = zi+yi;
            float Xor = 0.5f*Di, Xoi = -0.5f*Dr;
            float Xre = Xer + twc[c]*Xor + tws[c]*Xoi;
            float Xim = Xei + twc[c]*Xoi - tws[c]*Xor;
            if (c==0 && lane==0) Xim = 0.f;
            float r2 = Xre*Xre + Xim*Xim;
            bool ok = (r2 > 1e-30f);
            float inv = ok ? __builtin_amdgcn_rsqf(r2) : 0.f;
            float cc = ok ? Xre*inv : 1.f;
            float ss = Xim*inv;
            float m = magp[k];
            sr_[c] = m*cc; si_[c] = m*ss;
        }
        wsync();
        // stage S (+Nyquist) for the c2r pack mirror
#pragma unroll
        for (int c=0;c<4;++c){ int k=lane+64*c; br[P(k)]=sr_[c]; bi[P(k)]=si_[c]; }
        if (lane==0){
            float v = z0r - z0i;
            br[P(256)] = (v>=0.f)? magp[256] : -magp[256];
            bi[P(256)] = 0.f;
        }
        wsync();
        istft_tail(sr_, si_, br, bi, tw0, tw1, tw2, twc, tws, wA, wB,
                   lane, w*WSTRIDE + f*HOP, sacc);
    }
    __syncthreads();
    block_store(Xw, b, bx, sacc, tid);
}

// ============================================================
// k_inv0s: iteration-0 istft from (mag, angles_init)
// ============================================================
__global__ __launch_bounds__(128,4) void k_inv0s(const float* __restrict__ mag,
                                                 const float* __restrict__ ang,
                                                 const float* __restrict__ win,
                                                 float* __restrict__ Xw){
    __shared__ float sacc[SPAN];
    __shared__ float FR[2][272], FI[2][272];
    int tid = threadIdx.x, w = tid>>6, lane = tid&63;
    int b = blockIdx.y, bx = blockIdx.x;

    float *br = FR[w], *bi = FI[w];

    Tw tw0 = twset((float)lane * (1.f/256.f));
    Tw tw1 = twset((float)(lane>>2) * (1.f/64.f));
    Tw tw2 = twset((float)(lane>>4) * (1.f/16.f));
    float twc[4], tws[4], wA[4], wB[4];
#pragma unroll
    for (int c=0;c<4;++c){
        int k = lane + 64*c;
        float x = (float)k * (1.f/512.f);
        twc[c]=cosr(x); tws[c]=sinr(x);
        float2 wv = ((const float2*)win)[k];
        wA[c]=wv.x; wB[c]=wv.y;
    }
#pragma unroll
    for (int j=0;j<13;++j){ int u = tid + 128*j; if (u < SPAN) sacc[u]=0.f; }
    __syncthreads();

    const float* magb = mag + ((size_t)b*TFRAMES)*NBINS;
    const float* angb = ang + ((size_t)b*TFRAMES)*NBINS;
    int t0 = (bx*2 + w)*FPW;

#pragma unroll 1
    for (int f=0; f<FPW; ++f){
        int t = t0 + f;
        const float* magp = magb + (size_t)t*NBINS;
        const float* angp = angb + (size_t)t*NBINS;
        float sr_[4], si_[4];
#pragma unroll
        for (int c=0;c<4;++c){
            int k = lane + 64*c;
            float m = magp[k], a = angp[k];
            float sn, cs;
            sincosf(a, &sn, &cs);
            sr_[c] = m*cs;
            si_[c] = (c==0 && lane==0) ? 0.f : m*sn;
        }
#pragma unroll
        for (int c=0;c<4;++c){ int k=lane+64*c; br[P(k)]=sr_[c]; bi[P(k)]=si_[c]; }
        if (lane==0){
            br[P(256)] = magp[256]*cosf(angp[256]);
            bi[P(256)] = 0.f;
        }
        wsync();
        istft_tail(sr_, si_, br, bi, tw0, tw1, tw2, twc, tws, wA, wB,
                   lane, w*WSTRIDE + f*HOP, sacc);
    }
    __syncthreads();
    block_store(Xw, b, bx, sacc, tid);
}

// ============================================================
// k_out: normalize + crop
// ============================================================
__global__ __launch_bounds__(128) void k_out(const float* __restrict__ X,
                                             const float* __restrict__ wsq,
                                             float* __restrict__ out){
    int b = blockIdx.y;
    int idx = blockIdx.x*128 + threadIdx.x;
    if (idx >= LOUT/2) return;
    const float2* Xp = (const float2*)(X + (size_t)b*XPLEN + 256);
    const float2* Qp = (const float2*)(wsq + 256);
    float2 v = Xp[idx], q = Qp[idx];
    ((float2*)(out + (size_t)b*LOUT))[idx] = make_float2(v.x*q.x, v.y*q.y);
}

// ============================================================
extern "C" void kernel_launch(void* const* d_in, const int* in_sizes, int n_in,
                              void* d_out, int out_size, void* d_ws, size_t ws_size,
                              hipStream_t stream) {
    const float* mag  = (const float*)d_in[0];
    const float* ang0 = (const float*)d_in[1];
    const float* win  = (const float*)d_in[2];
    float* ws = (float*)d_ws;
    float* X[3] = { ws, ws + BXP, ws + 2*BXP };
    float* wsqi = ws + 3*BXP;
    float* outp = (float*)d_out;

    k_init<<<4096, 256, 0, stream>>>(win, wsqi, (float4*)ws);   // wsqi + zero X0,X1

    dim3 g(128, BATCH);
    k_inv0s<<<g, 128, 0, stream>>>(mag, ang0, win, X[0]);
    for (int it = 0; it < NITER; ++it){
        k_gl<<<g, 128, 0, stream>>>(X[it%3], X[(it+1)%3], X[(it+2)%3], mag, win, wsqi);
    }
    k_out<<<dim3(640, BATCH), 128, 0, stream>>>(X[NITER%3], wsqi, outp);
}

// Round 6
// 1492.297 us; speedup vs baseline: 2.8009x; 2.8009x over previous
//
#include <hip/hip_runtime.h>
#include <math.h>

#define BATCH 32
#define TFRAMES 1024
#define NBINS 257
#define NFFT 512
#define HOP 160
#define LOUT 163680
#define XPLEN 164192
#define NITER 32
#define FPW 4                        // frames per wave
#define WSTRIDE (FPW*HOP)            // 640
#define BSTRIDE (2*WSTRIDE)          // 1280 (block = 2 waves = 8 frames)
#define HALO (NFFT-HOP)              // 352
#define WSPAN (WSTRIDE+HALO)         // 992  per-wave OLA span
#define SPAN (BSTRIDE+HALO)          // 1632 per-block OLA span
#define NBLK 128                     // blocks per batch row
#define SLOT SPAN                    // slot stride in floats
#define SB ((size_t)NBLK*SLOT)       // per-batch slot floats
#define SBUF ((size_t)BATCH*SB)      // per-buffer floats (6684672)

#define P(i) ((i) + ((i) >> 5))      // LDS pad: 2-way max on stride-1/64 patterns

__device__ __forceinline__ float cosr(float x){ return __builtin_amdgcn_cosf(x); }
__device__ __forceinline__ float sinr(float x){ return __builtin_amdgcn_sinf(x); }
__device__ __forceinline__ void wsync(){
    __builtin_amdgcn_fence(__ATOMIC_SEQ_CST, "wavefront");
    __builtin_amdgcn_wave_barrier();
}

struct Tw { float c1,s1,c2,s2,c3,s3; };
__device__ __forceinline__ Tw twset(float x){
    Tw t; float c=cosr(x), s=sinr(x);
    t.c1=c; t.s1=s;
    t.c2=c*c-s*s; t.s2=2.f*c*s;
    t.c3=t.c2*c-t.s2*s; t.s3=t.c2*s+t.s2*c;
    return t;
}

template<int SIGN, bool TWID>
__device__ __forceinline__ void bfly4(const float xr[4], const float xi[4],
                                      const Tw& t, float yr[4], float yi[4]){
    constexpr float SG = (SIGN>0)?1.f:-1.f;
    float apc_r=xr[0]+xr[2], apc_i=xi[0]+xi[2];
    float amc_r=xr[0]-xr[2], amc_i=xi[0]-xi[2];
    float bpd_r=xr[1]+xr[3], bpd_i=xi[1]+xi[3];
    float bmd_r=xr[1]-xr[3], bmd_i=xi[1]-xi[3];
    yr[0]=apc_r+bpd_r; yi[0]=apc_i+bpd_i;
    float u2r=apc_r-bpd_r, u2i=apc_i-bpd_i;
    float u1r=amc_r-SG*bmd_i, u1i=amc_i+SG*bmd_r;
    float u3r=amc_r+SG*bmd_i, u3i=amc_i-SG*bmd_r;
    if (TWID){
        float s1=SG*t.s1, s2=SG*t.s2, s3=SG*t.s3;
        yr[1]=t.c1*u1r-s1*u1i; yi[1]=t.c1*u1i+s1*u1r;
        yr[2]=t.c2*u2r-s2*u2i; yi[2]=t.c2*u2i+s2*u2r;
        yr[3]=t.c3*u3r-s3*u3i; yi[3]=t.c3*u3i+s3*u3r;
    } else {
        yr[1]=u1r; yi[1]=u1i; yr[2]=u2r; yi[2]=u2i; yr[3]=u3r; yi[3]=u3i;
    }
}

// 256-pt complex FFT per wave, radix-4 Stockham, regs in/out, ONE LDS buffer
// (validated r4: same-wave DS ops complete in order; wsync pins compiler order)
template<int SIGN>
__device__ __forceinline__ void fft256reg(float xr[4], float xi[4],
                                          float* br, float* bi,
                                          const Tw& tw0, const Tw& tw1, const Tw& tw2,
                                          int lane){
    float yr[4], yi[4], ar[4], ai[4];
    bfly4<SIGN,true>(xr, xi, tw0, yr, yi);
    { int o = 4*lane;
#pragma unroll
      for (int c=0;c<4;++c){ br[P(o+c)]=yr[c]; bi[P(o+c)]=yi[c]; } }
    wsync();
#pragma unroll
    for (int c=0;c<4;++c){ ar[c]=br[P(lane+64*c)]; ai[c]=bi[P(lane+64*c)]; }
    wsync();
    bfly4<SIGN,true>(ar, ai, tw1, yr, yi);
    { int o = (lane&3) + 16*(lane>>2);
#pragma unroll
      for (int c=0;c<4;++c){ br[P(o+4*c)]=yr[c]; bi[P(o+4*c)]=yi[c]; } }
    wsync();
#pragma unroll
    for (int c=0;c<4;++c){ ar[c]=br[P(lane+64*c)]; ai[c]=bi[P(lane+64*c)]; }
    wsync();
    bfly4<SIGN,true>(ar, ai, tw2, yr, yi);
    { int o = (lane&15) + 64*(lane>>4);
#pragma unroll
      for (int c=0;c<4;++c){ br[P(o+16*c)]=yr[c]; bi[P(o+16*c)]=yi[c]; } }
    wsync();
#pragma unroll
    for (int c=0;c<4;++c){ ar[c]=br[P(lane+64*c)]; ai[c]=bi[P(lane+64*c)]; }
    wsync();
    bfly4<SIGN,false>(ar, ai, tw0, xr, xi);
}

// ============================================================
// k_init: wsqi (NOLA inverse) only — no buffer zeroing needed anywhere
// ============================================================
__global__ __launch_bounds__(256) void k_init(const float* __restrict__ win,
                                              float* __restrict__ wsqi){
    int i = blockIdx.x*256 + threadIdx.x;
    if (i < XPLEN){
        int n = i;
        int tmax = n / HOP; if (tmax > TFRAMES-1) tmax = TFRAMES-1;
        int tmin = (n - (NFFT-1) + (HOP-1)) / HOP; if (tmin < 0) tmin = 0;
        float acc = 0.f;
        for (int t = tmin; t <= tmax; ++t){ float w = win[n - t*HOP]; acc += w*w; }
        wsqi[i] = 1.0f / (acc > 1e-11f ? acc : 1.0f);
    }
}

// slot-reconstructed signal read: sample p of the padded waveform
__device__ __forceinline__ float xs(const float* __restrict__ Sb,
                                    const float* __restrict__ wsq, int p){
    int bxp = p / BSTRIDE, r = p - bxp*BSTRIDE;
    float a = 0.f;
    if (bxp < NBLK) a = Sb[(size_t)bxp*SLOT + r];
    if (r < HALO && bxp > 0) a += Sb[(size_t)(bxp-1)*SLOT + BSTRIDE + r];
    return a * wsq[p];
}
__device__ __forceinline__ float2 xs2(const float* __restrict__ Sb,
                                      const float* __restrict__ wsq, int p){ // p even
    int bxp = p / BSTRIDE, r = p - bxp*BSTRIDE;
    float2 acc = make_float2(0.f, 0.f);
    if (bxp < NBLK) acc = *(const float2*)(Sb + (size_t)bxp*SLOT + r);
    if (r < HALO && bxp > 0){
        float2 h = *(const float2*)(Sb + (size_t)(bxp-1)*SLOT + BSTRIDE + r);
        acc.x += h.x; acc.y += h.y;
    }
    float2 q = *(const float2*)(wsq + p);
    return make_float2(acc.x*q.x, acc.y*q.y);
}

// inverse half: pack regs -> inv FFT -> window -> private per-wave sacc (plain RMW)
__device__ __forceinline__ void inv_accum(float pr[4], float pi[4],
                                          float* br, float* bi,
                                          const Tw& tw0, const Tw& tw1, const Tw& tw2,
                                          const float wA[4], const float wB[4],
                                          int lane, int f, float2* sa2){
    fft256reg<+1>(pr, pi, br, bi, tw0, tw1, tw2, lane);
    constexpr float SC = 1.f/256.f;
    int base2 = f*(HOP/2);
#pragma unroll
    for (int c=0;c<4;++c){
        int u = base2 + lane + 64*c;
        float2 v = sa2[u];
        v.x += pr[c]*wA[c]*SC;
        v.y += pi[c]*wB[c]*SC;
        sa2[u] = v;
    }
    wsync();
}

// block writes its FULL span (merged s0+s1) into its private slot — plain stores
__device__ __forceinline__ void slot_store(float* __restrict__ Sw, int b, int bx,
                                           const float* s0, const float* s1, int tid){
    float2* slot2 = (float2*)(Sw + ((size_t)b*NBLK + bx)*SLOT);
    const float2* s0_2 = (const float2*)s0;
    const float2* s1_2 = (const float2*)s1;
#pragma unroll
    for (int j=0;j<7;++j){
        int u = tid + 128*j;                       // float2 index, need < SPAN/2=816
        if (u < SPAN/2){
            float2 v = make_float2(0.f, 0.f);
            if (u < WSPAN/2) v = s0_2[u];                       // s0 covers [0,992)
            if (u >= WSTRIDE/2){                                 // s1 covers [640,1632)
                float2 w1 = s1_2[u - WSTRIDE/2];
                v.x += w1.x; v.y += w1.y;
            }
            slot2[u] = v;
        }
    }
}

// ============================================================
// k_gl: one Griffin-Lim iteration. block = 2 waves x 4 frames.
// Reads slot buffer Sr (prev iter), writes slot buffer Sw. No atomics,
// no pre-zeroing, fully deterministic, every slot fully overwritten.
// ============================================================
__global__ __launch_bounds__(128,4) void k_gl(const float* __restrict__ Sr,
                                              float* __restrict__ Sw,
                                              const float* __restrict__ mag,
                                              const float* __restrict__ win,
                                              const float* __restrict__ wsq){
    __shared__ __align__(16) float sacc[2][WSPAN];
    __shared__ __align__(16) float FR[2][272], FI[2][272];
    int tid = threadIdx.x, w = tid>>6, lane = tid&63;
    int b = blockIdx.y, bx = blockIdx.x;

    float *br = FR[w], *bi = FI[w];
    float2* sa2 = (float2*)sacc[w];

    Tw tw0 = twset((float)lane * (1.f/256.f));
    Tw tw1 = twset((float)(lane>>2) * (1.f/64.f));
    Tw tw2 = twset((float)(lane>>4) * (1.f/16.f));
    float twc[4], tws[4], wA[4], wB[4];
#pragma unroll
    for (int c=0;c<4;++c){
        int k = lane + 64*c;
        float x = (float)k * (1.f/512.f);
        twc[c]=cosr(x); tws[c]=sinr(x);
        float2 wv = ((const float2*)win)[k];
        wA[c]=wv.x; wB[c]=wv.y;
    }
#pragma unroll
    for (int j=0;j<8;++j){ int u = lane + 64*j; if (u < WSPAN/2) sa2[u]=make_float2(0.f,0.f); }
    __syncthreads();

    const float* Sb = Sr + (size_t)b*SB;
    const float* magb = mag + ((size_t)b*TFRAMES)*NBINS;
    int t0 = (bx*2 + w)*FPW;

#pragma unroll 1
    for (int f=0; f<FPW; ++f){
        int t = t0 + f;
        float fr[4], fi[4];
        bool edge = (t < 2) | (t >= TFRAMES-2);
        if (!edge){
            int pb = t*HOP;
#pragma unroll
            for (int c=0;c<4;++c){
                int p = pb + 2*(lane + 64*c);
                float2 v = xs2(Sb, wsq, p);
                fr[c] = v.x*wA[c];
                fi[c] = v.y*wB[c];
            }
        } else {
#pragma unroll
            for (int c=0;c<4;++c){
                int m = lane + 64*c;
                int p0 = t*HOP + 2*m, p1 = p0+1;
                int n0 = (p0<256)?(512-p0):((p0>=LOUT+256)?(2*LOUT+510-p0):p0);
                int n1 = (p1<256)?(512-p1):((p1>=LOUT+256)?(2*LOUT+510-p1):p1);
                fr[c] = xs(Sb, wsq, n0)*wA[c];
                fi[c] = xs(Sb, wsq, n1)*wB[c];
            }
        }
        // forward FFT of packed frame
        fft256reg<-1>(fr, fi, br, bi, tw0, tw1, tw2, lane);
        wsync();
        // single mirror exchange of Z
#pragma unroll
        for (int c=0;c<4;++c){ int k=lane+64*c; br[P(k)]=fr[c]; bi[P(k)]=fi[c]; }
        wsync();
        float pr[4], pi[4];
        const float* magp = magb + (size_t)t*NBINS;
#pragma unroll
        for (int c=0;c<4;++c){
            int k = lane + 64*c;
            int mk = (256 - k) & 255;
            float yr = br[P(mk)], yi = bi[P(mk)];
            float zr = fr[c], zi = fi[c];
            // r2c unpack: X1 = X[k], X2 = X[256-k] = conj(Xe - Wbar^k Xo)
            float Xer = 0.5f*(zr+yr), Xei = 0.5f*(zi-yi);
            float Dr = zr-yr, Di = zi+yi;
            float Xor = 0.5f*Di, Xoi = -0.5f*Dr;          // Xo = -i*D/2
            float Or = twc[c]*Xor + tws[c]*Xoi;           // Wbar^k * Xo
            float Oi = twc[c]*Xoi - tws[c]*Xor;
            float X1r = Xer + Or, X1i = Xei + Oi;
            float X2r = Xer - Or, X2i = Oi - Xei;
            // unit phasors
            float q1 = X1r*X1r + X1i*X1i;
            bool ok1 = q1 > 1e-30f;
            float v1 = ok1 ? __builtin_amdgcn_rsqf(q1) : 0.f;
            float c1 = ok1 ? X1r*v1 : 1.f, s1 = X1i*v1;
            float q2 = X2r*X2r + X2i*X2i;
            bool ok2 = q2 > 1e-30f;
            float v2 = ok2 ? __builtin_amdgcn_rsqf(q2) : 0.f;
            float c2 = ok2 ? X2r*v2 : 1.f, s2 = X2i*v2;
            float m1 = magp[k], m2 = magp[256-k];
            float S1r = m1*c1, S1i = m1*s1;
            float S2r = m2*c2, S2i = m2*s2;
            // c2r pack: Z' = Xe' + i*Xo', Xo' = W^k*(S1 - conj(S2))/2
            float Aer = 0.5f*(S1r+S2r), Aei = 0.5f*(S1i-S2i);
            float Er = S1r - S2r, Ei = S1i + S2i;
            float Bor = 0.5f*(twc[c]*Er - tws[c]*Ei);
            float Boi = 0.5f*(twc[c]*Ei + tws[c]*Er);
            pr[c] = Aer - Boi;
            pi[c] = Aei + Bor;
        }
        wsync();
        inv_accum(pr, pi, br, bi, tw0, tw1, tw2, wA, wB, lane, f, sa2);
    }
    __syncthreads();
    slot_store(Sw, b, bx, sacc[0], sacc[1], tid);
}

// ============================================================
// k_inv0s: iteration-0 istft from (mag, angles_init) -> slots
// ============================================================
__global__ __launch_bounds__(128,4) void k_inv0s(const float* __restrict__ mag,
                                                 const float* __restrict__ ang,
                                                 const float* __restrict__ win,
                                                 float* __restrict__ Sw){
    __shared__ __align__(16) float sacc[2][WSPAN];
    __shared__ __align__(16) float FR[2][272], FI[2][272];
    int tid = threadIdx.x, w = tid>>6, lane = tid&63;
    int b = blockIdx.y, bx = blockIdx.x;

    float *br = FR[w], *bi = FI[w];
    float2* sa2 = (float2*)sacc[w];

    Tw tw0 = twset((float)lane * (1.f/256.f));
    Tw tw1 = twset((float)(lane>>2) * (1.f/64.f));
    Tw tw2 = twset((float)(lane>>4) * (1.f/16.f));
    float twc[4], tws[4], wA[4], wB[4];
#pragma unroll
    for (int c=0;c<4;++c){
        int k = lane + 64*c;
        float x = (float)k * (1.f/512.f);
        twc[c]=cosr(x); tws[c]=sinr(x);
        float2 wv = ((const float2*)win)[k];
        wA[c]=wv.x; wB[c]=wv.y;
    }
#pragma unroll
    for (int j=0;j<8;++j){ int u = lane + 64*j; if (u < WSPAN/2) sa2[u]=make_float2(0.f,0.f); }
    __syncthreads();

    const float* magb = mag + ((size_t)b*TFRAMES)*NBINS;
    const float* angb = ang + ((size_t)b*TFRAMES)*NBINS;
    int t0 = (bx*2 + w)*FPW;

#pragma unroll 1
    for (int f=0; f<FPW; ++f){
        int t = t0 + f;
        const float* magp = magb + (size_t)t*NBINS;
        const float* angp = angb + (size_t)t*NBINS;
        float sr_[4], si_[4];
#pragma unroll
        for (int c=0;c<4;++c){
            int k = lane + 64*c;
            float m = magp[k], a = angp[k];
            float sn, cs;
            sincosf(a, &sn, &cs);
            sr_[c] = m*cs;
            si_[c] = (c==0 && lane==0) ? 0.f : m*sn;
        }
        // stage S (+Nyquist) for the c2r pack mirror
#pragma unroll
        for (int c=0;c<4;++c){ int k=lane+64*c; br[P(k)]=sr_[c]; bi[P(k)]=si_[c]; }
        if (lane==0){
            br[P(256)] = magp[256]*cosf(angp[256]);
            bi[P(256)] = 0.f;
        }
        wsync();
        float pr[4], pi[4];
#pragma unroll
        for (int c=0;c<4;++c){
            int k = lane + 64*c;
            float yr = br[P(256-k)], yi = bi[P(256-k)];
            float Aer = 0.5f*(sr_[c]+yr), Aei = 0.5f*(si_[c]-yi);
            float Er = sr_[c]-yr, Ei = si_[c]+yi;
            float Bor = 0.5f*(twc[c]*Er - tws[c]*Ei);
            float Boi = 0.5f*(twc[c]*Ei + tws[c]*Er);
            pr[c] = Aer - Boi;
            pi[c] = Aei + Bor;
        }
        wsync();
        inv_accum(pr, pi, br, bi, tw0, tw1, tw2, wA, wB, lane, f, sa2);
    }
    __syncthreads();
    slot_store(Sw, b, bx, sacc[0], sacc[1], tid);
}

// ============================================================
// k_out: reconstruct from slots + NOLA normalize + crop
// ============================================================
__global__ __launch_bounds__(128) void k_out(const float* __restrict__ S,
                                             const float* __restrict__ wsq,
                                             float* __restrict__ out){
    int b = blockIdx.y;
    int idx = blockIdx.x*128 + threadIdx.x;
    if (idx >= LOUT/2) return;
    const float* Sb = S + (size_t)b*SB;
    float2 v = xs2(Sb, wsq, 256 + 2*idx);
    ((float2*)(out + (size_t)b*LOUT))[idx] = v;
}

// ============================================================
extern "C" void kernel_launch(void* const* d_in, const int* in_sizes, int n_in,
                              void* d_out, int out_size, void* d_ws, size_t ws_size,
                              hipStream_t stream) {
    const float* mag  = (const float*)d_in[0];
    const float* ang0 = (const float*)d_in[1];
    const float* win  = (const float*)d_in[2];
    float* ws = (float*)d_ws;
    float* S[2] = { ws, ws + SBUF };
    float* wsqi = ws + 2*SBUF;
    float* outp = (float*)d_out;

    k_init<<<(XPLEN + 255)/256, 256, 0, stream>>>(win, wsqi);

    dim3 g(NBLK, BATCH);
    k_inv0s<<<g, 128, 0, stream>>>(mag, ang0, win, S[0]);
    for (int it = 0; it < NITER; ++it){
        k_gl<<<g, 128, 0, stream>>>(S[it%2], S[(it+1)%2], mag, win, wsqi);
    }
    k_out<<<dim3(640, BATCH), 128, 0, stream>>>(S[NITER%2], wsqi, outp);
}